// Round 1
// baseline (8574.258 us; speedup 1.0000x reference)
//
#include <hip/hip_runtime.h>

// LSTM_Block: B=512, T=168, I=64, H1=H2=256. fp32 baseline.
// Fused per-timestep kernel: g = [x_t | h_{t-1}] @ WP + bias -> gates -> c,h.
// WP packed as [K][jh][gate] so each thread grabs its 4 gate coeffs as float4.

#define HDIM 256
#define BDIM 512
#define TDIM 168
#define IDIM 64
#define BT 16   // batch tile per block
#define JT 64   // jh tile per block (x4 gates = 256 gemm cols)

__global__ void prep_weights(const float* __restrict__ W_ih, const float* __restrict__ W_hh,
                             const float* __restrict__ b_ih, const float* __restrict__ b_hh,
                             float* __restrict__ WP, float* __restrict__ BP,
                             int K, int I) {
    int total = K * 1024;
    for (int idx = blockIdx.x * blockDim.x + threadIdx.x; idx < total;
         idx += gridDim.x * blockDim.x) {
        int k = idx >> 10;
        int col = idx & 1023;
        int jh = col >> 2, g = col & 3;
        int j = g * HDIM + jh;                 // gate order i,f,g,o
        float v = (k < I) ? W_ih[(size_t)j * I + k] : W_hh[(size_t)j * HDIM + (k - I)];
        WP[idx] = v;
    }
    int t = blockIdx.x * blockDim.x + threadIdx.x;
    if (t < 1024) {
        int jh = t >> 2, g = t & 3;
        int j = g * HDIM + jh;
        BP[t] = b_ih[j] + b_hh[j];
    }
}

__launch_bounds__(256, 4)
__global__ void lstm_step(const float* __restrict__ in, long in_stride,
                          const float* __restrict__ h_in,
                          float* __restrict__ h_out,
                          float* __restrict__ c,
                          float* __restrict__ out, long out_stride,
                          const float* __restrict__ WP, const float* __restrict__ BP,
                          int K, int I) {
    __shared__ float At[32][20];    // [k][b], pad to 20 floats: b128-aligned reads
    __shared__ float Wt[32][256];   // [k][jh*4+g]

    const int tid = threadIdx.x;
    const int b0  = blockIdx.x * BT;
    const int jh0 = blockIdx.y * JT;
    const int jh_l = tid >> 2;      // 0..63
    const int bg   = tid & 3;       // 4 b's each

    float acc[4][4];
#pragma unroll
    for (int b = 0; b < 4; ++b)
#pragma unroll
        for (int g = 0; g < 4; ++g) acc[b][g] = 0.f;

    for (int kc = 0; kc < K; kc += 32) {
        // stage A tile: 16 b x 32 k (transposed into LDS)
#pragma unroll
        for (int r = 0; r < 2; ++r) {
            int i = tid + r * 256;
            int b_l = i >> 5, k_l = i & 31;
            int k_g = kc + k_l;
            float v;
            if (k_g < I) v = in[(long)(b0 + b_l) * in_stride + k_g];
            else         v = h_in[(size_t)(b0 + b_l) * HDIM + (k_g - I)];
            At[k_l][b_l] = v;
        }
        // stage W tile: 32 k x 256 cols (float4 coalesced)
#pragma unroll
        for (int r = 0; r < 8; ++r) {
            int i = tid + r * 256;
            int k_l = i >> 6, c_l = i & 63;
            float4 w = *(const float4*)(WP + (size_t)(kc + k_l) * 1024 + (size_t)jh0 * 4 + c_l * 4);
            *(float4*)&Wt[k_l][c_l * 4] = w;
        }
        __syncthreads();
#pragma unroll
        for (int k = 0; k < 32; ++k) {
            float4 a = *(const float4*)&At[k][bg * 4];
            float4 w = *(const float4*)&Wt[k][jh_l * 4];
            acc[0][0] += a.x * w.x; acc[0][1] += a.x * w.y; acc[0][2] += a.x * w.z; acc[0][3] += a.x * w.w;
            acc[1][0] += a.y * w.x; acc[1][1] += a.y * w.y; acc[1][2] += a.y * w.z; acc[1][3] += a.y * w.w;
            acc[2][0] += a.z * w.x; acc[2][1] += a.z * w.y; acc[2][2] += a.z * w.z; acc[2][3] += a.z * w.w;
            acc[3][0] += a.w * w.x; acc[3][1] += a.w * w.y; acc[3][2] += a.w * w.z; acc[3][3] += a.w * w.w;
        }
        __syncthreads();
    }

    // epilogue: gates + state update
    const float4 bp = *(const float4*)(BP + (size_t)(jh0 + jh_l) * 4);
    const int jh_g = jh0 + jh_l;
#pragma unroll
    for (int b = 0; b < 4; ++b) {
        int b_g = b0 + bg * 4 + b;
        float gi = acc[b][0] + bp.x;
        float gf = acc[b][1] + bp.y;
        float gg = acc[b][2] + bp.z;
        float go = acc[b][3] + bp.w;
        float i_ = 1.f / (1.f + __expf(-gi));
        float f_ = 1.f / (1.f + __expf(-gf));
        float g_ = tanhf(gg);
        float o_ = 1.f / (1.f + __expf(-go));
        size_t ci = (size_t)b_g * HDIM + jh_g;
        float cn = f_ * c[ci] + i_ * g_;
        c[ci] = cn;
        float h = o_ * tanhf(cn);
        h_out[ci] = h;
        out[(size_t)b_g * out_stride + jh_g] = h;
    }
}

extern "C" void kernel_launch(void* const* d_in, const int* in_sizes, int n_in,
                              void* d_out, int out_size, void* d_ws, size_t ws_size,
                              hipStream_t stream) {
    const float* x     = (const float*)d_in[0];
    const float* W_ih1 = (const float*)d_in[1];
    const float* W_hh1 = (const float*)d_in[2];
    const float* b_ih1 = (const float*)d_in[3];
    const float* b_hh1 = (const float*)d_in[4];
    const float* W_ih2 = (const float*)d_in[5];
    const float* W_hh2 = (const float*)d_in[6];
    const float* b_ih2 = (const float*)d_in[7];
    const float* b_hh2 = (const float*)d_in[8];
    float* out2 = (float*)d_out;

    // workspace carve (fp32), 256B aligned
    size_t off = 0;
    char* base = (char*)d_ws;
    auto alloc = [&](size_t elems) {
        float* p = (float*)(base + off);
        off += elems * sizeof(float);
        off = (off + 255) & ~(size_t)255;
        return p;
    };
    const int K1 = IDIM + HDIM;   // 320
    const int K2 = HDIM + HDIM;   // 512
    float* WP1 = alloc((size_t)K1 * 1024);
    float* BP1 = alloc(1024);
    float* WP2 = alloc((size_t)K2 * 1024);
    float* BP2 = alloc(1024);
    // zero-init block: hA1, c1, hA2, c2 contiguous (each 512*256*4 = 524288 B, 256-aligned)
    float* hA1 = alloc((size_t)BDIM * HDIM);
    float* c1  = alloc((size_t)BDIM * HDIM);
    float* hA2 = alloc((size_t)BDIM * HDIM);
    float* c2  = alloc((size_t)BDIM * HDIM);
    float* hB1 = alloc((size_t)BDIM * HDIM);
    float* hB2 = alloc((size_t)BDIM * HDIM);
    float* out1 = alloc((size_t)BDIM * TDIM * HDIM);
    (void)ws_size; (void)in_sizes; (void)n_in; (void)out_size;

    hipMemsetAsync(hA1, 0, 4 * (size_t)BDIM * HDIM * sizeof(float), stream);

    prep_weights<<<dim3(1280), dim3(256), 0, stream>>>(W_ih1, W_hh1, b_ih1, b_hh1, WP1, BP1, K1, IDIM);
    prep_weights<<<dim3(2048), dim3(256), 0, stream>>>(W_ih2, W_hh2, b_ih2, b_hh2, WP2, BP2, K2, HDIM);

    dim3 grid(BDIM / BT, HDIM / JT);   // 32 x 4
    dim3 blk(256);

    // layer 1
    for (int t = 0; t < TDIM; ++t) {
        const float* h_in = (t & 1) ? hB1 : hA1;
        float* h_out      = (t & 1) ? hA1 : hB1;
        lstm_step<<<grid, blk, 0, stream>>>(
            x + (size_t)t * IDIM, (long)TDIM * IDIM,
            h_in, h_out, c1,
            out1 + (size_t)t * HDIM, (long)TDIM * HDIM,
            WP1, BP1, K1, IDIM);
    }
    // layer 2
    for (int t = 0; t < TDIM; ++t) {
        const float* h_in = (t & 1) ? hB2 : hA2;
        float* h_out      = (t & 1) ? hA2 : hB2;
        lstm_step<<<grid, blk, 0, stream>>>(
            out1 + (size_t)t * HDIM, (long)TDIM * HDIM,
            h_in, h_out, c2,
            d_out ? out2 + (size_t)t * HDIM : nullptr, (long)TDIM * HDIM,
            WP2, BP2, K2, HDIM);
    }
}

// Round 2
// 3214.055 us; speedup vs baseline: 2.6677x; 2.6677x over previous
//
#include <hip/hip_runtime.h>

// LSTM_Block B=512,T=168,I=64,H=256x2. MFMA bf16x3 step kernel, diagonal
// layer pipeline: dispatch s runs L1(t=s) and L2(t=s-1). 169 dispatches.

#define B_ 512
#define T_ 168
#define I_ 64
#define H_ 256

typedef __attribute__((ext_vector_type(8))) short short8;
typedef __attribute__((ext_vector_type(4))) float f32x4;
typedef unsigned short u16;

__device__ __forceinline__ u16 f2bf(float f) {           // RNE
    unsigned u = __float_as_uint(f);
    return (u16)((u + 0x7fff + ((u >> 16) & 1)) >> 16);
}
__device__ __forceinline__ float bf2f(u16 b) { return __uint_as_float(((unsigned)b) << 16); }

// W packed [col][K] (col = gate*256 + jh, gate order i,f,g,o), bf16 hi/lo.
__global__ void prep_w(const float* __restrict__ W_ih, const float* __restrict__ W_hh,
                       const float* __restrict__ b_ih, const float* __restrict__ b_hh,
                       u16* __restrict__ Whi, u16* __restrict__ Wlo, float* __restrict__ BP,
                       int K, int I) {
    int j = blockIdx.y;
    int k = blockIdx.x * 256 + threadIdx.x;
    if (k < K) {
        float v = (k < I) ? W_ih[(size_t)j * I + k] : W_hh[(size_t)j * H_ + (k - I)];
        u16 hi = f2bf(v);
        u16 lo = f2bf(v - bf2f(hi));
        Whi[(size_t)j * K + k] = hi;
        Wlo[(size_t)j * K + k] = lo;
    }
    if (blockIdx.x == 0 && threadIdx.x == 0) BP[j] = b_ih[j] + b_hh[j];
}

__global__ void prep_x(const float* __restrict__ x, u16* __restrict__ Xhi, u16* __restrict__ Xlo, int n) {
    for (int i = blockIdx.x * blockDim.x + threadIdx.x; i < n; i += gridDim.x * blockDim.x) {
        float v = x[i];
        u16 hi = f2bf(v);
        Xhi[i] = hi;
        Xlo[i] = f2bf(v - bf2f(hi));
    }
}

// One wave per block. Wave: 32 b (2 M-tiles) x 16 jh x 4 gates.
// A: lane reads Act[b0+(l&15)][k0 + (l>>4)*8 + 0..7]  (16B)
// B: lane reads W[col0+(l&15)][same k]                (16B)
// D: col=lane&15 (jh), row=(lane>>4)*4+i (b).
template<int NK, int NK0, bool OUT>
__device__ __forceinline__ void step_body(
    const u16* __restrict__ a0hi, const u16* __restrict__ a0lo, int a0s, long a0base,
    const u16* __restrict__ a1hi, const u16* __restrict__ a1lo,
    u16* __restrict__ hwhi, u16* __restrict__ hwlo,
    float* __restrict__ cbuf,
    const u16* __restrict__ Whi, const u16* __restrict__ Wlo,
    const float* __restrict__ BP, float* __restrict__ outp, int t)
{
    constexpr int K = NK * 32;
    const int lane = threadIdx.x;
    const int b0  = blockIdx.x * 32;
    const int jh0 = blockIdx.y * 16;
    const int lm  = lane & 15;
    const int lk  = (lane >> 4) << 3;

    f32x4 acc[2][4];
#pragma unroll
    for (int m = 0; m < 2; ++m)
#pragma unroll
        for (int g = 0; g < 4; ++g) acc[m][g] = (f32x4){0.f, 0.f, 0.f, 0.f};

    size_t woff = (size_t)(jh0 + lm) * K + lk;

    auto do_k = [&](short8 ah0, short8 al0, short8 ah1, short8 al1) {
#pragma unroll
        for (int g = 0; g < 4; ++g) {
            const size_t wg = woff + (size_t)g * (256 * (size_t)K);
            short8 wh = *(const short8*)(Whi + wg);
            short8 wl = *(const short8*)(Wlo + wg);
            acc[0][g] = __builtin_amdgcn_mfma_f32_16x16x32_bf16(ah0, wh, acc[0][g], 0, 0, 0);
            acc[0][g] = __builtin_amdgcn_mfma_f32_16x16x32_bf16(al0, wh, acc[0][g], 0, 0, 0);
            acc[0][g] = __builtin_amdgcn_mfma_f32_16x16x32_bf16(ah0, wl, acc[0][g], 0, 0, 0);
            acc[1][g] = __builtin_amdgcn_mfma_f32_16x16x32_bf16(ah1, wh, acc[1][g], 0, 0, 0);
            acc[1][g] = __builtin_amdgcn_mfma_f32_16x16x32_bf16(al1, wh, acc[1][g], 0, 0, 0);
            acc[1][g] = __builtin_amdgcn_mfma_f32_16x16x32_bf16(ah1, wl, acc[1][g], 0, 0, 0);
        }
        woff += 32;
    };

    // k in [0, NK0*32): from src0 (x_t for L1, out1[t] for L2)
    size_t a0off = (size_t)a0base + (size_t)(b0 + lm) * a0s + lk;
#pragma unroll
    for (int ks = 0; ks < NK0; ++ks) {
        short8 ah0 = *(const short8*)(a0hi + a0off);
        short8 al0 = *(const short8*)(a0lo + a0off);
        short8 ah1 = *(const short8*)(a0hi + a0off + (size_t)16 * a0s);
        short8 al1 = *(const short8*)(a0lo + a0off + (size_t)16 * a0s);
        a0off += 32;
        do_k(ah0, al0, ah1, al1);
    }
    // k in [NK0*32, K): from own h (recurrent)
    size_t a1off = (size_t)(b0 + lm) * H_ + lk;
#pragma unroll 4
    for (int ks = NK0; ks < NK; ++ks) {
        short8 ah0 = *(const short8*)(a1hi + a1off);
        short8 al0 = *(const short8*)(a1lo + a1off);
        short8 ah1 = *(const short8*)(a1hi + a1off + 16 * H_);
        short8 al1 = *(const short8*)(a1lo + a1off + 16 * H_);
        a1off += 32;
        do_k(ah0, al0, ah1, al1);
    }

    // epilogue: gates -> c,h
    const int jh = jh0 + lm;
    const float bi = BP[jh], bf = BP[256 + jh], bg = BP[512 + jh], bo = BP[768 + jh];
#pragma unroll
    for (int m = 0; m < 2; ++m) {
#pragma unroll
        for (int i = 0; i < 4; ++i) {
            const int b = b0 + m * 16 + ((lane >> 4) << 2) + i;
            float gi = acc[m][0][i] + bi;
            float gf = acc[m][1][i] + bf;
            float gg = acc[m][2][i] + bg;
            float go = acc[m][3][i] + bo;
            float si = 1.f / (1.f + __expf(-gi));
            float sf = 1.f / (1.f + __expf(-gf));
            float tg = tanhf(gg);
            float so = 1.f / (1.f + __expf(-go));
            const size_t ci = (size_t)b * H_ + jh;
            float cn = sf * cbuf[ci] + si * tg;
            cbuf[ci] = cn;
            float h = so * tanhf(cn);
            u16 hh = f2bf(h);
            hwhi[ci] = hh;
            hwlo[ci] = f2bf(h - bf2f(hh));
            if (OUT) outp[((size_t)b * T_ + t) * H_ + jh] = h;
        }
    }
}

struct StepArgs {
    const u16 *x_hi, *x_lo;        // X split, [B][T][I]
    const u16 *h1r_hi, *h1r_lo;    // H1 read parity (also L2 src0)
    u16 *h1w_hi, *h1w_lo;          // H1 write parity
    const u16 *h2r_hi, *h2r_lo;
    u16 *h2w_hi, *h2w_lo;
    float *c1, *c2;
    const u16 *W1hi, *W1lo, *W2hi, *W2lo;
    const float *BP1, *BP2;
    float *out;
    int t1, t2;
};

__global__ __launch_bounds__(64) void lstm_step_k(StepArgs a) {
    if (blockIdx.z == 0) {
        if (a.t1 >= T_) return;
        step_body<10, 2, false>(a.x_hi, a.x_lo, T_ * I_, (long)a.t1 * I_,
                                a.h1r_hi, a.h1r_lo, a.h1w_hi, a.h1w_lo, a.c1,
                                a.W1hi, a.W1lo, a.BP1, nullptr, 0);
    } else {
        if (a.t2 < 0) return;
        step_body<16, 8, true>(a.h1r_hi, a.h1r_lo, H_, 0,
                               a.h2r_hi, a.h2r_lo, a.h2w_hi, a.h2w_lo, a.c2,
                               a.W2hi, a.W2lo, a.BP2, a.out, a.t2);
    }
}

extern "C" void kernel_launch(void* const* d_in, const int* in_sizes, int n_in,
                              void* d_out, int out_size, void* d_ws, size_t ws_size,
                              hipStream_t stream) {
    const float* x     = (const float*)d_in[0];
    const float* W_ih1 = (const float*)d_in[1];
    const float* W_hh1 = (const float*)d_in[2];
    const float* b_ih1 = (const float*)d_in[3];
    const float* b_hh1 = (const float*)d_in[4];
    const float* W_ih2 = (const float*)d_in[5];
    const float* W_hh2 = (const float*)d_in[6];
    const float* b_ih2 = (const float*)d_in[7];
    const float* b_hh2 = (const float*)d_in[8];
    (void)in_sizes; (void)n_in; (void)out_size; (void)ws_size;

    size_t off = 0;
    char* base = (char*)d_ws;
    auto alloc = [&](size_t bytes) { void* p = base + off; off = (off + bytes + 255) & ~(size_t)255; return p; };

    const int K1 = I_ + H_;   // 320
    const int K2 = H_ + H_;   // 512
    u16* W1hi = (u16*)alloc((size_t)1024 * K1 * 2);
    u16* W1lo = (u16*)alloc((size_t)1024 * K1 * 2);
    u16* W2hi = (u16*)alloc((size_t)1024 * K2 * 2);
    u16* W2lo = (u16*)alloc((size_t)1024 * K2 * 2);
    float* BP1 = (float*)alloc(1024 * 4);
    float* BP2 = (float*)alloc(1024 * 4);
    u16* Xhi = (u16*)alloc((size_t)B_ * T_ * I_ * 2);
    u16* Xlo = (u16*)alloc((size_t)B_ * T_ * I_ * 2);

    // zero-init state block: H1hi[2],H1lo[2],H2hi[2],H2lo[2] (bf16) + C1,C2 (fp32)
    char* state0 = (char*)alloc(0);
    const size_t HB = (size_t)B_ * H_ * 2;  // 256 KB (bf16 buffer)
    u16* H1hi[2] = {(u16*)alloc(HB), (u16*)alloc(HB)};
    u16* H1lo[2] = {(u16*)alloc(HB), (u16*)alloc(HB)};
    u16* H2hi[2] = {(u16*)alloc(HB), (u16*)alloc(HB)};
    u16* H2lo[2] = {(u16*)alloc(HB), (u16*)alloc(HB)};
    float* C1 = (float*)alloc((size_t)B_ * H_ * 4);
    float* C2 = (float*)alloc((size_t)B_ * H_ * 4);
    size_t stateBytes = (char*)base + off - state0;

    hipMemsetAsync(state0, 0, stateBytes, stream);
    prep_w<<<dim3(2, 1024), 256, 0, stream>>>(W_ih1, W_hh1, b_ih1, b_hh1, W1hi, W1lo, BP1, K1, I_);
    prep_w<<<dim3(2, 1024), 256, 0, stream>>>(W_ih2, W_hh2, b_ih2, b_hh2, W2hi, W2lo, BP2, K2, H_);
    prep_x<<<2048, 256, 0, stream>>>(x, Xhi, Xlo, B_ * T_ * I_);

    dim3 grid(B_ / 32, H_ / 16, 2);   // 16 x 16 x 2 = 512 blocks
    for (int s = 0; s <= T_; ++s) {
        const int t1 = s, t2 = s - 1;
        const int wp1 = t1 & 1, rp1 = wp1 ^ 1;
        const int wp2 = (t2 >= 0) ? (t2 & 1) : 0, rp2 = wp2 ^ 1;
        StepArgs a;
        a.x_hi = Xhi; a.x_lo = Xlo;
        a.h1r_hi = H1hi[rp1]; a.h1r_lo = H1lo[rp1];
        a.h1w_hi = H1hi[wp1]; a.h1w_lo = H1lo[wp1];
        a.h2r_hi = H2hi[rp2]; a.h2r_lo = H2lo[rp2];
        a.h2w_hi = H2hi[wp2]; a.h2w_lo = H2lo[wp2];
        a.c1 = C1; a.c2 = C2;
        a.W1hi = W1hi; a.W1lo = W1lo; a.W2hi = W2hi; a.W2lo = W2lo;
        a.BP1 = BP1; a.BP2 = BP2;
        a.out = (float*)d_out;
        a.t1 = t1; a.t2 = t2;
        lstm_step_k<<<grid, 64, 0, stream>>>(a);
    }
}